// Round 1
// baseline (94.735 us; speedup 1.0000x reference)
//
#include <hip/hip_runtime.h>

// S4D kernel generation:
//   out[h, l] = 2 * Re( sum_n Ccp[h,n] * exp(dtA[h,n] * l) ),  l = 0..L-1
// with Ccp = C * (exp(dtA) - 1) / A,  dtA = dt * (-exp(log_A_real) + i*A_imag).
//
// Strategy: one block per h. Thread t owns l in {t, t+256, ..., t+15*256}
// (coalesced stores). Per state n: init z = Ccp * exp(dtA * t) via one
// exp + sincos (phase reduced mod 2pi in fp64 to handle |phase| up to ~4e4),
// then a 16-step geometric recurrence z *= w, w = exp(dtA * 256) precomputed
// per (h,n) in LDS. Recurrence depth 16 keeps accumulated rounding ~15 ulp.

#define HH  1024
#define NN  32          // N/2 states
#define LL  4096
#define TPB 256
#define CH  (LL / TPB)  // 16 l-values per thread

__global__ __launch_bounds__(TPB, 4) void s4d_kernel(
    const float* __restrict__ log_dt,
    const float* __restrict__ C,          // (H, NN, 2) interleaved re/im
    const float* __restrict__ log_A_real, // (H, NN)
    const float* __restrict__ A_imag,     // (H, NN)
    float* __restrict__ out)              // (H, LL)
{
    const int h = blockIdx.x;
    const int t = threadIdx.x;

    __shared__ float  s_dtAre[NN];
    __shared__ float  s_cre[NN], s_cim[NN];   // Ccp = C*(exp(dtA)-1)/A
    __shared__ float  s_wre[NN], s_wim[NN];   // w = exp(dtA * TPB)
    __shared__ double s_rev[NN];              // dt*Aim/(2pi): revolutions per unit l

    const float dt = __expf(log_dt[h]);

    if (t < NN) {
        const int n = t;
        const float Are = -__expf(log_A_real[h * NN + n]);
        const float Aim = A_imag[h * NN + n];
        const float dtAre = dt * Are;
        const float dtAim = dt * Aim;          // |dtAim| <= ~9.8, safe for sincosf

        // f = (exp(dtA) - 1) / A   (complex)
        const float e = __expf(dtAre);
        float s, c;
        __sincosf(dtAim, &s, &c);
        const float nre = e * c - 1.0f;
        const float nim = e * s;
        const float inv = 1.0f / (Are * Are + Aim * Aim);
        const float fre = (nre * Are + nim * Aim) * inv;
        const float fim = (nim * Are - nre * Aim) * inv;

        const float Cre = C[(h * NN + n) * 2 + 0];
        const float Cim = C[(h * NN + n) * 2 + 1];
        s_cre[n] = Cre * fre - Cim * fim;
        s_cim[n] = Cre * fim + Cim * fre;
        s_dtAre[n] = dtAre;

        // phase step in revolutions (fp64 so mod-1 reduction is exact enough
        // for phases up to dtAim * 4096 ~ 4e4 rad)
        const double rev1 = (double)dt * (double)Aim * 0.15915494309189535; // /(2pi)
        s_rev[n] = rev1;

        // w = exp(dtA * TPB): magnitude via expf, phase reduced mod 1 rev
        double rw = rev1 * (double)TPB;
        rw -= floor(rw);
        const float thw = (float)rw * 6.2831853071795864f;
        float sw, cw;
        __sincosf(thw, &sw, &cw);
        const float ew = __expf(dtAre * (float)TPB);
        s_wre[n] = ew * cw;
        s_wim[n] = ew * sw;
    }
    __syncthreads();

    float acc[CH];
#pragma unroll
    for (int i = 0; i < CH; ++i) acc[i] = 0.0f;

    const float tf = (float)t;

#pragma unroll 2
    for (int n = 0; n < NN; ++n) {
        // init z = Ccp * exp(dtA * t), phase mod 2pi in fp64
        double rv = s_rev[n] * (double)t;
        rv -= floor(rv);
        const float th = (float)rv * 6.2831853071795864f;
        float si, ci;
        __sincosf(th, &si, &ci);
        const float er = __expf(s_dtAre[n] * tf);
        const float zr0 = er * ci;
        const float zi0 = er * si;
        const float cr = s_cre[n], cim = s_cim[n];
        float zr = cr * zr0 - cim * zi0;
        float zi = cr * zi0 + cim * zr0;

        const float wr = s_wre[n], wi = s_wim[n];
#pragma unroll
        for (int i = 0; i < CH; ++i) {
            acc[i] += zr;
            const float nzr = zr * wr - zi * wi;
            const float nzi = zr * wi + zi * wr;
            zr = nzr;
            zi = nzi;
        }
    }

    float* o = out + (size_t)h * LL + t;
#pragma unroll
    for (int i = 0; i < CH; ++i) o[i * TPB] = 2.0f * acc[i];
}

extern "C" void kernel_launch(void* const* d_in, const int* in_sizes, int n_in,
                              void* d_out, int out_size, void* d_ws, size_t ws_size,
                              hipStream_t stream) {
    const float* log_dt     = (const float*)d_in[0];
    const float* C          = (const float*)d_in[1];
    const float* log_A_real = (const float*)d_in[2];
    const float* A_imag     = (const float*)d_in[3];
    // d_in[4] is L (device scalar); L=4096 is fixed by the problem spec and
    // cannot be read host-side under graph capture, so it is compiled in.
    float* out = (float*)d_out;

    const int H = in_sizes[0];  // 1024
    s4d_kernel<<<dim3(H), dim3(TPB), 0, stream>>>(log_dt, C, log_A_real, A_imag, out);
}

// Round 2
// 75.649 us; speedup vs baseline: 1.2523x; 1.2523x over previous
//
#include <hip/hip_runtime.h>

// S4D kernel generation:
//   out[h, l] = 2 * Re( sum_n Ccp[h,n] * w_n^l ),  w_n = exp(dt*A_n),  l = 0..4095
//
// Round-2 structure:
//  - 2 h per block (256 thr), 128 threads per h, each thread owns l = lane + 128*i,
//    i = 0..31 (coalesced stores, init transcendentals amortized over 32 l's).
//  - Hot loop uses the REAL second-order recurrence for x_i = Re(z0 * W^i),
//    W = w^128:  x_{i+1} = 2Re(W)*x_i - |W|^2*x_{i-1}   (3 ops/state/step),
//    with two states packed into float2 ext-vectors so the backend emits
//    v_pk_fma_f32 / v_pk_mul_f32 / v_pk_add_f32 (1.5 inst/state/step).
//  - Phase of w^l reduced mod 2pi in fp64 (|phase| up to ~4e4 rad), so sincosf
//    sees a small angle; |W|^2 = exp(2*128*dtAre) computed directly (exact mag).

#define NN  32          // N/2 states
#define LL  4096
#define TPB 256
#define HPB 2           // h per block
#define TPH (TPB/HPB)   // 128 threads per h
#define CH  (LL/TPH)    // 32 l-values per thread

typedef float f32x2 __attribute__((ext_vector_type(2)));

__global__ __launch_bounds__(TPB, 2) void s4d_kernel(
    const float* __restrict__ log_dt,
    const float* __restrict__ C,          // (H, NN, 2) interleaved re/im
    const float* __restrict__ log_A_real, // (H, NN)
    const float* __restrict__ A_imag,     // (H, NN)
    float* __restrict__ out)              // (H, LL)
{
    const int h0   = blockIdx.x * HPB;
    const int t    = threadIdx.x;
    const int sub  = t / TPH;     // which h within block
    const int lane = t % TPH;     // base l
    const int h    = h0 + sub;

    __shared__ float  s_cr[HPB][NN], s_ci[HPB][NN];   // Ccp = C*(exp(dtA)-1)/A
    __shared__ float  s_dtAre[HPB][NN];
    __shared__ double s_rev[HPB][NN];                 // dt*Aim/(2pi) revolutions per l
    __shared__ float  s_Wr[HPB][NN], s_Wi[HPB][NN];   // W = w^TPH
    __shared__ float  s_a[HPB][NN], s_m[HPB][NN];     // a = 2Re(W), m = |W|^2

    if (t < HPB * NN) {
        const int ss = t / NN;
        const int n  = t % NN;
        const int hh = h0 + ss;
        const float dt    = __expf(log_dt[hh]);
        const float Are   = -__expf(log_A_real[hh * NN + n]);
        const float Aim   = A_imag[hh * NN + n];
        const float dtAre = dt * Are;
        const float dtAim = dt * Aim;          // |.| <= ~9.8

        // f = (exp(dtA) - 1) / A
        const float e = __expf(dtAre);
        float s, c;
        __sincosf(dtAim, &s, &c);
        const float nre = e * c - 1.0f;
        const float nim = e * s;
        const float inv = 1.0f / (Are * Are + Aim * Aim);
        const float fre = (nre * Are + nim * Aim) * inv;
        const float fim = (nim * Are - nre * Aim) * inv;

        const float Cre = C[(hh * NN + n) * 2 + 0];
        const float Cim = C[(hh * NN + n) * 2 + 1];
        s_cr[ss][n] = Cre * fre - Cim * fim;
        s_ci[ss][n] = Cre * fim + Cim * fre;
        s_dtAre[ss][n] = dtAre;

        const double rev1 = (double)dt * (double)Aim * 0.15915494309189535; // /(2pi)
        s_rev[ss][n] = rev1;

        // W = w^TPH: magnitude exact via expf, phase reduced mod 1 rev in fp64
        double rw = rev1 * (double)TPH;
        rw -= floor(rw);
        float sw, cw;
        __sincosf((float)rw * 6.2831853071795864f, &sw, &cw);
        const float ew = __expf(dtAre * (float)TPH);
        const float Wr = ew * cw, Wi = ew * sw;
        s_Wr[ss][n] = Wr;
        s_Wi[ss][n] = Wi;
        s_a[ss][n]  = 2.0f * Wr;
        s_m[ss][n]  = ew * ew;                 // |W|^2, exact magnitude
    }
    __syncthreads();

    f32x2 acc[CH];
#pragma unroll
    for (int i = 0; i < CH; ++i) acc[i] = (f32x2){0.0f, 0.0f};

    const float lf = (float)lane;

    for (int np = 0; np < NN; np += 2) {
        float x0[2], x1[2];
#pragma unroll
        for (int j = 0; j < 2; ++j) {
            const int n = np + j;
            // z0 = Ccp * w^lane, phase mod 2pi in fp64
            double rv = s_rev[sub][n] * (double)lane;
            rv -= floor(rv);
            float si, ci;
            __sincosf((float)rv * 6.2831853071795864f, &si, &ci);
            const float er = __expf(s_dtAre[sub][n] * lf);
            const float zr = er * ci, zi = er * si;
            const float cr = s_cr[sub][n], cim = s_ci[sub][n];
            const float xr0 = cr * zr - cim * zi;   // Re(z0)
            const float xi0 = cr * zi + cim * zr;   // Im(z0)
            x0[j] = xr0;
            x1[j] = xr0 * s_Wr[sub][n] - xi0 * s_Wi[sub][n]; // Re(z0*W)
        }
        const f32x2 a2 = { s_a[sub][np],  s_a[sub][np + 1] };
        const f32x2 m2 = { -s_m[sub][np], -s_m[sub][np + 1] };
        f32x2 xp = { x0[0], x0[1] };   // x_i
        f32x2 xc = { x1[0], x1[1] };   // x_{i+1}
#pragma unroll
        for (int i = 0; i < CH; i += 2) {
            acc[i]     += xp;
            acc[i + 1] += xc;
            xp = __builtin_elementwise_fma(a2, xc, m2 * xp);  // x_{i+2}
            xc = __builtin_elementwise_fma(a2, xp, m2 * xc);  // x_{i+3}
        }
    }

    float* o = out + (size_t)h * LL + lane;
#pragma unroll
    for (int i = 0; i < CH; ++i)
        o[(size_t)i * TPH] = 2.0f * (acc[i].x + acc[i].y);
}

extern "C" void kernel_launch(void* const* d_in, const int* in_sizes, int n_in,
                              void* d_out, int out_size, void* d_ws, size_t ws_size,
                              hipStream_t stream) {
    const float* log_dt     = (const float*)d_in[0];
    const float* C          = (const float*)d_in[1];
    const float* log_A_real = (const float*)d_in[2];
    const float* A_imag     = (const float*)d_in[3];
    // d_in[4] is L (device scalar); L=4096 fixed by the problem spec.
    float* out = (float*)d_out;

    const int H = in_sizes[0];  // 1024
    s4d_kernel<<<dim3(H / HPB), dim3(TPB), 0, stream>>>(log_dt, C, log_A_real, A_imag, out);
}